// Round 19
// baseline (94.632 us; speedup 1.0000x reference)
//
#include <hip/hip_runtime.h>
#include <hip/hip_bf16.h>
#include <math.h>

#define BATCH 8192
#define F 256
#define G 32
#define W 512
#define NCHUNK 132
#define NPER 66
#define NPERL 33   // periods per K-split block (66 chunks / 2)

typedef float f32x4 __attribute__((ext_vector_type(4)));
typedef short s16x8 __attribute__((ext_vector_type(8)));
typedef long long i64x2 __attribute__((ext_vector_type(2)));
typedef unsigned long long u64;

__device__ __forceinline__ short f2bf(float f) {
  unsigned int u = __builtin_bit_cast(unsigned int, f);
  u += 0x7fffu + ((u >> 16) & 1u);
  return (short)(u >> 16);
}

__device__ __forceinline__ float bf2f(unsigned short h) {
  unsigned int u = ((unsigned int)h) << 16;
  return __builtin_bit_cast(float, u);
}

__device__ __forceinline__ float knotv(int i) {
  int j = i - 3;
  j = j < 0 ? 0 : (j > 29 ? 29 : j);
  return (float)j * (1.0f / 29.0f);
}

__device__ __forceinline__ float fdiv_fast(float a, float b) {
  return a * __builtin_amdgcn_rcpf(b);
}

// ---------------- merged pre-pass: B relayout + basis ----------------
__global__ __launch_bounds__(256) void pre_build(
    const float* __restrict__ coeffs, const float* __restrict__ skip_w,
    const float* __restrict__ inp, const float* __restrict__ shift,
    const float* __restrict__ lscale,
    short* __restrict__ Bws, unsigned long long* __restrict__ nvq,
    unsigned char* __restrict__ s0q)
{
  __shared__ float T[64][17];
  __shared__ float sfc[16], sfh[16];
  const int tid = threadIdx.x;

  if (blockIdx.x < 2112) {
    const int gid = blockIdx.x * 256 + tid;
    const int lane = gid & 63;
    const int kk = (gid >> 6) & 1;
    const int nf = (gid >> 7) & 3;
    const int wn = (gid >> 9) & 1;
    const int nt = (gid >> 10) & 3;
    const int c  = gid >> 12;
    const int w  = nt * 128 + wn * 64 + nf * 16 + (lane & 15);
    const int kl = kk * 32 + (lane >> 4) * 8;
    const float* src = (c < 128) ? (coeffs + (size_t)(c * 64 + kl) * W + w)
                                 : (skip_w + (size_t)((c - 128) * 64 + kl) * W + w);
    s16x8 h;
    #pragma unroll
    for (int j = 0; j < 8; ++j) h[j] = f2bf(src[(size_t)j * W]);
    ((s16x8*)Bws)[gid] = h;
    return;
  }

  const int bb = blockIdx.x - 2112;
  const int b0 = (bb & 127) * 64;
  const int f0 = (bb >> 7) * 16;

  {
    const int r = tid >> 2, q = tid & 3;
    float4 v = *(const float4*)(inp + (size_t)(b0 + r) * F + f0 + q * 4);
    T[r][q * 4 + 0] = v.x;
    T[r][q * 4 + 1] = v.y;
    T[r][q * 4 + 2] = v.z;
    T[r][q * 4 + 3] = v.w;
  }
  if (tid < 16) {
    float ls = lscale[f0 + tid];
    sfc[tid] = fmaxf(ls, 0.0f) + __logf(1.0f + __expf(-fabsf(ls))) + 0.001f;
    sfh[tid] = shift[f0 + tid];
  }
  __syncthreads();

  const int lane = tid & 63;
  const int wid = tid >> 6;
  #pragma unroll
  for (int j = 0; j < 4; ++j) {
    const int fl = wid * 4 + j;
    const int f = f0 + fl;
    const float z = (T[lane][fl] - sfh[fl]) * sfc[fl];
    const float sg = 1.0f / (1.0f + __expf(-z));
    int s0 = (int)(sg * 29.0f);
    s0 = s0 < 0 ? 0 : (s0 > 28 ? 28 : s0);
    const int sp = s0 + 3;
    float Nv[4], lef[4], rig[4];
    Nv[0] = 1.0f;
    #pragma unroll
    for (int r = 1; r <= 3; ++r) {
      lef[r] = sg - knotv(sp + 1 - r);
      rig[r] = knotv(sp + r) - sg;
      float saved = 0.0f;
      #pragma unroll
      for (int jj = 0; jj < r; ++jj) {
        float temp = fdiv_fast(Nv[jj], rig[jj + 1] + lef[r - jj]);
        Nv[jj] = saved + rig[jj + 1] * temp;
        saved = lef[r - jj] * temp;
      }
      Nv[r] = saved;
    }
    const u64 nv =
        (u64)(unsigned short)f2bf(Nv[0])
      | ((u64)(unsigned short)f2bf(Nv[1]) << 16)
      | ((u64)(unsigned short)f2bf(Nv[2]) << 32)
      | ((u64)(unsigned short)f2bf(Nv[3]) << 48);
    nvq[(size_t)f * BATCH + b0 + lane] = nv;
    s0q[(size_t)f * BATCH + b0 + lane] = (unsigned char)s0;
  }
}

// ---------------- A staging ----------------
__device__ __forceinline__ void stage_nv(short* __restrict__ Ab, int cc,
    int stoff, int hi, int bp, int m0,
    unsigned long long nv, int s0, const float* __restrict__ inp)
{
  short* base = Ab + stoff;
  if (cc < 128) {
    const int pp = s0 & 7, ga = s0 >> 3;
    const int s = 16 * pp, shl = s & 63;
    const unsigned long long a = nv << shl;
    const unsigned long long b = (nv >> (63 - shl)) >> 1;
    const bool hs = (s >= 64);
    i64x2 d0, d1, z;
    d0[0] = hs ? 0ll : (long long)a;
    d0[1] = hs ? (long long)a : (long long)b;
    d1[0] = hs ? (long long)b : 0ll;
    d1[1] = 0ll;
    z[0] = 0ll; z[1] = 0ll;
    *(i64x2*)(base + ga * 128) = d0;
    *(i64x2*)(base + ((ga + 1) & 3) * 128) = d1;
    *(i64x2*)(base + ((ga + 2) & 3) * 128) = z;
    *(i64x2*)(base + ((ga + 3) & 3) * 128) = z;
  } else {
    const int sb = (cc - 128) * 64 + hi * 32;
    const float* ip = inp + (size_t)(m0 + bp) * F + sb;
    #pragma unroll
    for (int lq = 0; lq < 4; ++lq) {
      s16x8 h;
      #pragma unroll
      for (int j = 0; j < 8; ++j) h[j] = f2bf(ip[lq * 8 + j]);
      *(s16x8*)(base + lq * 128) = h;
    }
  }
}

// ---------------- main GEMM v18: K-split x2, 4 blocks/CU; bf16 partials to Cws ----------------
__global__ __launch_bounds__(256, 2) void kan_gemm_v18(
    const float* __restrict__ inp, const short* __restrict__ Bws,
    const unsigned long long* __restrict__ nvq, const unsigned char* __restrict__ s0q,
    const float* __restrict__ bias, const float* __restrict__ skip_b,
    short* __restrict__ Cws)
{
  __shared__ short Abuf[2][8192];

  const int tid = threadIdx.x;
  const int lane = tid & 63;
  const int wid = tid >> 6;
  const int kh = wid >> 1;
  const int nh = wid & 1;

  // 1024 blocks = 8 XCDs x 128; per XCD: fixed (nt, kb) -> 1.03MB B slice L2-resident
  const int nb = ((blockIdx.x & 7) << 7) | (blockIdx.x >> 3);
  const int nt = nb >> 8;                  // 0..3
  const int kb = (nb >> 7) & 1;            // K half
  const int mt = nb & 127;
  const int m0 = mt * 64, n0 = nt * 128;
  const int cbase = kb * 66;               // first chunk of this block's K range

  const int ci = tid >> 7;
  const int hi = (tid >> 6) & 1;
  const int bp = tid & 63;
  const int mg = bp >> 4, l15b = bp & 15;
  const int stoff = ci * 4096 + ((mg * 2 + hi) * 64 + l15b) * 8;

  f32x4 acc[4][4];
  #pragma unroll
  for (int i = 0; i < 4; ++i)
    #pragma unroll
    for (int j = 0; j < 4; ++j)
      acc[i][j] = (f32x4){0.f, 0.f, 0.f, 0.f};

  const short* bq = Bws + (size_t)((((cbase + kh) * 4 + nt) * 2 + nh) * 8) * 512 + lane * 8;

#define LOADB(BS) do {                                                          \
    _Pragma("unroll")                                                           \
    for (int nf = 0; nf < 4; ++nf)                                              \
      _Pragma("unroll")                                                         \
      for (int kk = 0; kk < 2; ++kk)                                            \
        BS[nf * 2 + kk] = *(const s16x8*)(bq + (nf * 2 + kk) * 512);            \
    bq += 65536;                                                                \
  } while (0)

#define PREF(NVL, S0L, PTGT) do {                                               \
    const int cc_ = cbase + 2 * (PTGT) + ci;                                    \
    if ((PTGT) < NPERL && cc_ < 128) {                                          \
      const size_t ix_ = (size_t)(2 * cc_ + hi) * BATCH + m0 + bp;              \
      NVL = nvq[ix_];                                                           \
      S0L = (int)s0q[ix_];                                                      \
    }                                                                           \
  } while (0)

#define MMAC(AB, BS)                                                            \
    _Pragma("unroll")                                                           \
    for (int kk = 0; kk < 2; ++kk)                                              \
      _Pragma("unroll")                                                         \
      for (int mf = 0; mf < 4; ++mf) {                                          \
        s16x8 af = *(const s16x8*)&(AB)[kh * 4096 + ((mf * 2 + kk) * 64 + lane) * 8]; \
        _Pragma("unroll")                                                       \
        for (int nf = 0; nf < 4; ++nf)                                          \
          acc[mf][nf] = __builtin_amdgcn_mfma_f32_16x16x32_bf16(                \
              af, BS[nf * 2 + kk], acc[mf][nf], 0, 0, 0);                       \
      }

#define PERIOD(P_, ACUR, ANXT, BCUR, BNXT, NVU, S0U, NVL, S0L) do {             \
    asm volatile("s_waitcnt lgkmcnt(0)" ::: "memory");                          \
    __builtin_amdgcn_s_barrier();                                               \
    PREF(NVL, S0L, (P_) + 2);                                                   \
    if ((P_) + 1 < NPERL) {                                                     \
      LOADB(BNXT);                                                              \
      stage_nv(ANXT, cbase + 2 * ((P_) + 1) + ci, stoff, hi, bp, m0, NVU, S0U, inp); \
    }                                                                           \
    __builtin_amdgcn_s_setprio(1);                                              \
    MMAC(ACUR, BCUR);                                                           \
    __builtin_amdgcn_s_setprio(0);                                              \
  } while (0)

  s16x8 bA[8], bB[8];
  unsigned long long nvA = 0, nvB = 0;
  int s0A = 0, s0B = 0;

  PREF(nvA, s0A, 0);
  LOADB(bA);
  stage_nv(&Abuf[0][0], cbase + ci, stoff, hi, bp, m0, nvA, s0A, inp);
  PREF(nvB, s0B, 1);

  for (int p = 0; p + 1 < NPERL; p += 2) {
    PERIOD(p,     (&Abuf[0][0]), (&Abuf[1][0]), bA, bB, nvB, s0B, nvA, s0A);
    PERIOD(p + 1, (&Abuf[1][0]), (&Abuf[0][0]), bB, bA, nvA, s0A, nvB, s0B);
  }
  PERIOD(NPERL - 1, (&Abuf[0][0]), (&Abuf[1][0]), bA, bB, nvB, s0B, nvA, s0A);
#undef PERIOD
#undef MMAC
#undef PREF
#undef LOADB

  // ---------- epilogue: cross-kh reduce; kb=0 adds bias+skip_b; bf16 partial out ----------
  __syncthreads();
  float* red = (float*)&Abuf[0][0];
  const int l15 = lane & 15;
  const int lq = lane >> 4;
  if (kh == 1) {
    #pragma unroll
    for (int mf = 0; mf < 4; ++mf)
      #pragma unroll
      for (int nf = 0; nf < 4; ++nf)
        *(f32x4*)&red[nh * 4096 + (mf * 4 + nf) * 256 + lane * 4] = acc[mf][nf];
  }
  __syncthreads();
  if (kh == 0) {
    short* Cp = Cws + (size_t)kb * BATCH * W;
    #pragma unroll
    for (int nf = 0; nf < 4; ++nf) {
      const int col = n0 + nh * 64 + nf * 16 + l15;
      const float badd = (kb == 0) ? (bias[col] + skip_b[col]) : 0.0f;
      #pragma unroll
      for (int mf = 0; mf < 4; ++mf) {
        f32x4 part = *(const f32x4*)&red[nh * 4096 + (mf * 4 + nf) * 256 + lane * 4];
        const int r0 = m0 + mf * 16 + lq * 4;
        #pragma unroll
        for (int r = 0; r < 4; ++r)
          Cp[(size_t)(r0 + r) * W + col] = f2bf(acc[mf][nf][r] + part[r] + badd);
      }
    }
  }
}

// ---------------- LN + GeLU from two bf16 partials -> fp32 out ----------------
__global__ __launch_bounds__(256, 1) void ln_gelu_bf2(
    const short* __restrict__ Cws, float* __restrict__ out,
    const float* __restrict__ gamma, const float* __restrict__ beta)
{
  const int lane = threadIdx.x & 63;
  const int wid = threadIdx.x >> 6;
  const int row = blockIdx.x * 4 + wid;
  const short* p0 = Cws + (size_t)row * W + lane * 8;
  const short* p1 = p0 + (size_t)BATCH * W;
  s16x8 h0 = *(const s16x8*)p0;
  s16x8 h1 = *(const s16x8*)p1;
  float v[8];
  #pragma unroll
  for (int j = 0; j < 8; ++j)
    v[j] = bf2f((unsigned short)h0[j]) + bf2f((unsigned short)h1[j]);
  float s = 0.f, q = 0.f;
  #pragma unroll
  for (int j = 0; j < 8; ++j) { s += v[j]; q += v[j] * v[j]; }
  #pragma unroll
  for (int m = 1; m < 64; m <<= 1) {
    s += __shfl_xor(s, m);
    q += __shfl_xor(q, m);
  }
  const float mu = s * (1.0f / 512.0f);
  const float var = q * (1.0f / 512.0f) - mu * mu;
  const float inv = rsqrtf(var + 1e-5f);
  const float4 g0 = *(const float4*)(gamma + lane * 8);
  const float4 g1 = *(const float4*)(gamma + lane * 8 + 4);
  const float4 b0 = *(const float4*)(beta + lane * 8);
  const float4 b1 = *(const float4*)(beta + lane * 8 + 4);
  float gm[8] = {g0.x, g0.y, g0.z, g0.w, g1.x, g1.y, g1.z, g1.w};
  float bt[8] = {b0.x, b0.y, b0.z, b0.w, b1.x, b1.y, b1.z, b1.w};
  float o[8];
  #pragma unroll
  for (int j = 0; j < 8; ++j) {
    float x = (v[j] - mu) * inv * gm[j] + bt[j];
    o[j] = 0.5f * x * (1.0f + erff(x * 0.70710678f));
  }
  float* po = out + (size_t)row * W + lane * 8;
  float4 w0 = {o[0], o[1], o[2], o[3]};
  float4 w1 = {o[4], o[5], o[6], o[7]};
  *(float4*)po = w0;
  *(float4*)(po + 4) = w1;
}

// ---------------- mid-tier GEMM (no-split, fp32 out) — R16 proven path ----------------
__global__ __launch_bounds__(256, 2) void kan_gemm_v9f(
    const float* __restrict__ inp, const short* __restrict__ Bws,
    const unsigned long long* __restrict__ nvq, const unsigned char* __restrict__ s0q,
    const float* __restrict__ bias, const float* __restrict__ skip_b,
    float* __restrict__ outf)
{
  __shared__ short Abuf[2][8192];

  const int tid = threadIdx.x;
  const int lane = tid & 63;
  const int wid = tid >> 6;
  const int kh = wid >> 1;
  const int nh = wid & 1;

  const int nb = ((blockIdx.x & 7) << 6) | (blockIdx.x >> 3);
  const int mt = nb >> 2, nt = nb & 3;
  const int m0 = mt * 64, n0 = nt * 128;

  const int ci = tid >> 7;
  const int hi = (tid >> 6) & 1;
  const int bp = tid & 63;
  const int mg = bp >> 4, l15b = bp & 15;
  const int stoff = ci * 4096 + ((mg * 2 + hi) * 64 + l15b) * 8;

  f32x4 acc[4][4];
  #pragma unroll
  for (int i = 0; i < 4; ++i)
    #pragma unroll
    for (int j = 0; j < 4; ++j)
      acc[i][j] = (f32x4){0.f, 0.f, 0.f, 0.f};

  const short* bq = Bws + (size_t)(((kh * 4 + nt) * 2 + nh) * 8) * 512 + lane * 8;

#define LOADB(BS) do {                                                          \
    _Pragma("unroll")                                                           \
    for (int nf = 0; nf < 4; ++nf)                                              \
      _Pragma("unroll")                                                         \
      for (int kk = 0; kk < 2; ++kk)                                            \
        BS[nf * 2 + kk] = *(const s16x8*)(bq + (nf * 2 + kk) * 512);            \
    bq += 65536;                                                                \
  } while (0)

#define PREF(NVL, S0L, PTGT) do {                                               \
    const int cc_ = 2 * (PTGT) + ci;                                            \
    if ((PTGT) < NPER && cc_ < 128) {                                           \
      const size_t ix_ = (size_t)(2 * cc_ + hi) * BATCH + m0 + bp;              \
      NVL = nvq[ix_];                                                           \
      S0L = (int)s0q[ix_];                                                      \
    }                                                                           \
  } while (0)

#define MMAC(AB, BS)                                                            \
    _Pragma("unroll")                                                           \
    for (int kk = 0; kk < 2; ++kk)                                              \
      _Pragma("unroll")                                                         \
      for (int mf = 0; mf < 4; ++mf) {                                          \
        s16x8 af = *(const s16x8*)&(AB)[kh * 4096 + ((mf * 2 + kk) * 64 + lane) * 8]; \
        _Pragma("unroll")                                                       \
        for (int nf = 0; nf < 4; ++nf)                                          \
          acc[mf][nf] = __builtin_amdgcn_mfma_f32_16x16x32_bf16(                \
              af, BS[nf * 2 + kk], acc[mf][nf], 0, 0, 0);                       \
      }

#define PERIOD(P_, ACUR, ANXT, BCUR, BNXT, NVU, S0U, NVL, S0L) do {             \
    asm volatile("s_waitcnt lgkmcnt(0)" ::: "memory");                          \
    __builtin_amdgcn_s_barrier();                                               \
    PREF(NVL, S0L, (P_) + 2);                                                   \
    if ((P_) + 1 < NPER) {                                                      \
      LOADB(BNXT);                                                              \
      stage_nv(ANXT, 2 * ((P_) + 1) + ci, stoff, hi, bp, m0, NVU, S0U, inp);    \
    }                                                                           \
    __builtin_amdgcn_s_setprio(1);                                              \
    MMAC(ACUR, BCUR);                                                           \
    __builtin_amdgcn_s_setprio(0);                                              \
  } while (0)

  s16x8 bA[8], bB[8];
  unsigned long long nvA = 0, nvB = 0;
  int s0A = 0, s0B = 0;

  PREF(nvA, s0A, 0);
  LOADB(bA);
  stage_nv(&Abuf[0][0], ci, stoff, hi, bp, m0, nvA, s0A, inp);
  PREF(nvB, s0B, 1);

  for (int p = 0; p < NPER; p += 2) {
    PERIOD(p,     (&Abuf[0][0]), (&Abuf[1][0]), bA, bB, nvB, s0B, nvA, s0A);
    PERIOD(p + 1, (&Abuf[1][0]), (&Abuf[0][0]), bB, bA, nvA, s0A, nvB, s0B);
  }
#undef PERIOD
#undef MMAC
#undef PREF
#undef LOADB

  __syncthreads();
  float* red = (float*)&Abuf[0][0];
  const int l15 = lane & 15;
  const int lq = lane >> 4;
  if (kh == 1) {
    #pragma unroll
    for (int mf = 0; mf < 4; ++mf)
      #pragma unroll
      for (int nf = 0; nf < 4; ++nf)
        *(f32x4*)&red[nh * 4096 + (mf * 4 + nf) * 256 + lane * 4] = acc[mf][nf];
  }
  __syncthreads();
  if (kh == 0) {
    #pragma unroll
    for (int nf = 0; nf < 4; ++nf) {
      const int col = n0 + nh * 64 + nf * 16 + l15;
      const float badd = bias[col] + skip_b[col];
      #pragma unroll
      for (int mf = 0; mf < 4; ++mf) {
        f32x4 part = *(const f32x4*)&red[nh * 4096 + (mf * 4 + nf) * 256 + lane * 4];
        const int r0 = m0 + mf * 16 + lq * 4;
        #pragma unroll
        for (int r = 0; r < 4; ++r)
          outf[(size_t)(r0 + r) * W + col] = acc[mf][nf][r] + part[r] + badd;
      }
    }
  }
}

// ---------------- LN + GeLU in-place fp32 (mid-tier path) ----------------
__global__ __launch_bounds__(256, 1) void ln_gelu(
    float* __restrict__ out, const float* __restrict__ gamma,
    const float* __restrict__ beta)
{
  const int lane = threadIdx.x & 63;
  const int wid = threadIdx.x >> 6;
  const int row = blockIdx.x * 4 + wid;
  float* p = out + (size_t)row * W + lane * 8;
  float4 a = *(const float4*)p;
  float4 b = *(const float4*)(p + 4);
  float v[8] = {a.x, a.y, a.z, a.w, b.x, b.y, b.z, b.w};
  float s = 0.f, q = 0.f;
  #pragma unroll
  for (int j = 0; j < 8; ++j) { s += v[j]; q += v[j] * v[j]; }
  #pragma unroll
  for (int m = 1; m < 64; m <<= 1) {
    s += __shfl_xor(s, m);
    q += __shfl_xor(q, m);
  }
  const float mu = s * (1.0f / 512.0f);
  const float var = q * (1.0f / 512.0f) - mu * mu;
  const float inv = rsqrtf(var + 1e-5f);
  const float4 g0 = *(const float4*)(gamma + lane * 8);
  const float4 g1 = *(const float4*)(gamma + lane * 8 + 4);
  const float4 b0 = *(const float4*)(beta + lane * 8);
  const float4 b1 = *(const float4*)(beta + lane * 8 + 4);
  float gm[8] = {g0.x, g0.y, g0.z, g0.w, g1.x, g1.y, g1.z, g1.w};
  float bt[8] = {b0.x, b0.y, b0.z, b0.w, b1.x, b1.y, b1.z, b1.w};
  float o[8];
  #pragma unroll
  for (int j = 0; j < 8; ++j) {
    float x = (v[j] - mu) * inv * gm[j] + bt[j];
    o[j] = 0.5f * x * (1.0f + erff(x * 0.70710678f));
  }
  float4 w0 = {o[0], o[1], o[2], o[3]};
  float4 w1 = {o[4], o[5], o[6], o[7]};
  *(float4*)p = w0;
  *(float4*)(p + 4) = w1;
}

extern "C" void kernel_launch(void* const* d_in, const int* in_sizes, int n_in,
                              void* d_out, int out_size, void* d_ws, size_t ws_size,
                              hipStream_t stream) {
  (void)in_sizes; (void)n_in; (void)out_size;
  const float* inp    = (const float*)d_in[0];
  const float* shift  = (const float*)d_in[1];
  const float* lscale = (const float*)d_in[2];
  const float* coeffs = (const float*)d_in[3];
  const float* bias   = (const float*)d_in[4];
  const float* skip_w = (const float*)d_in[5];
  const float* skip_b = (const float*)d_in[6];
  const float* gamma  = (const float*)d_in[7];
  const float* beta   = (const float*)d_in[8];
  float* out = (float*)d_out;

  const size_t needB  = (size_t)NCHUNK * 4 * 16384;        // 8,650,752
  const size_t needNV = (size_t)F * BATCH * 8;             // 16,777,216
  const size_t needS0 = (size_t)F * BATCH;                 //  2,097,152
  const size_t needC2 = (size_t)2 * BATCH * W * 2;         // 16,777,216

  if (ws_size >= needB + needNV + needS0 + needC2) {
    short* Bws = (short*)d_ws;
    unsigned long long* nvq = (unsigned long long*)((char*)d_ws + needB);
    unsigned char* s0q = (unsigned char*)((char*)d_ws + needB + needNV);
    short* Cws = (short*)((char*)d_ws + needB + needNV + needS0);
    pre_build<<<dim3(4160), dim3(256), 0, stream>>>(
        coeffs, skip_w, inp, shift, lscale, Bws, nvq, s0q);
    kan_gemm_v18<<<dim3(1024), dim3(256), 0, stream>>>(
        inp, Bws, nvq, s0q, bias, skip_b, Cws);
    ln_gelu_bf2<<<dim3(BATCH / 4), dim3(256), 0, stream>>>(Cws, out, gamma, beta);
  } else {
    short* Bws = (short*)d_ws;
    unsigned long long* nvq = (unsigned long long*)((char*)d_ws + needB);
    unsigned char* s0q = (unsigned char*)((char*)d_ws + needB + needNV);
    pre_build<<<dim3(4160), dim3(256), 0, stream>>>(
        coeffs, skip_w, inp, shift, lscale, Bws, nvq, s0q);
    kan_gemm_v9f<<<dim3(512), dim3(256), 0, stream>>>(
        inp, Bws, nvq, s0q, bias, skip_b, out);
    ln_gelu<<<dim3(BATCH / 4), dim3(256), 0, stream>>>(out, gamma, beta);
  }
}

// Round 20
// 87.227 us; speedup vs baseline: 1.0849x; 1.0849x over previous
//
#include <hip/hip_runtime.h>
#include <hip/hip_bf16.h>
#include <math.h>

#define BATCH 8192
#define F 256
#define G 32
#define W 512
#define NCHUNK 132
#define NPER 66

typedef float f32x4 __attribute__((ext_vector_type(4)));
typedef short s16x8 __attribute__((ext_vector_type(8)));
typedef long long i64x2 __attribute__((ext_vector_type(2)));
typedef unsigned long long u64;

__device__ __forceinline__ short f2bf(float f) {
  unsigned int u = __builtin_bit_cast(unsigned int, f);
  u += 0x7fffu + ((u >> 16) & 1u);
  return (short)(u >> 16);
}

__device__ __forceinline__ float bf2f(unsigned short h) {
  unsigned int u = ((unsigned int)h) << 16;
  return __builtin_bit_cast(float, u);
}

__device__ __forceinline__ float knotv(int i) {
  int j = i - 3;
  j = j < 0 ? 0 : (j > 29 ? 29 : j);
  return (float)j * (1.0f / 29.0f);
}

__device__ __forceinline__ float fdiv_fast(float a, float b) {
  return a * __builtin_amdgcn_rcpf(b);
}

// ---------------- merged pre-pass ----------------
__global__ __launch_bounds__(256) void pre_build(
    const float* __restrict__ coeffs, const float* __restrict__ skip_w,
    const float* __restrict__ inp, const float* __restrict__ shift,
    const float* __restrict__ lscale,
    short* __restrict__ Bws, unsigned long long* __restrict__ nvq,
    unsigned char* __restrict__ s0q)
{
  __shared__ float T[64][17];
  __shared__ float sfc[16], sfh[16];
  const int tid = threadIdx.x;

  if (blockIdx.x < 2112) {
    const int gid = blockIdx.x * 256 + tid;
    const int lane = gid & 63;
    const int kk = (gid >> 6) & 1;
    const int nf = (gid >> 7) & 3;
    const int wn = (gid >> 9) & 1;
    const int nt = (gid >> 10) & 3;
    const int c  = gid >> 12;
    const int w  = nt * 128 + wn * 64 + nf * 16 + (lane & 15);
    const int kl = kk * 32 + (lane >> 4) * 8;
    const float* src = (c < 128) ? (coeffs + (size_t)(c * 64 + kl) * W + w)
                                 : (skip_w + (size_t)((c - 128) * 64 + kl) * W + w);
    s16x8 h;
    #pragma unroll
    for (int j = 0; j < 8; ++j) h[j] = f2bf(src[(size_t)j * W]);
    ((s16x8*)Bws)[gid] = h;
    return;
  }

  const int bb = blockIdx.x - 2112;
  const int b0 = (bb & 127) * 64;
  const int f0 = (bb >> 7) * 16;

  {
    const int r = tid >> 2, q = tid & 3;
    float4 v = *(const float4*)(inp + (size_t)(b0 + r) * F + f0 + q * 4);
    T[r][q * 4 + 0] = v.x;
    T[r][q * 4 + 1] = v.y;
    T[r][q * 4 + 2] = v.z;
    T[r][q * 4 + 3] = v.w;
  }
  if (tid < 16) {
    float ls = lscale[f0 + tid];
    sfc[tid] = fmaxf(ls, 0.0f) + __logf(1.0f + __expf(-fabsf(ls))) + 0.001f;
    sfh[tid] = shift[f0 + tid];
  }
  __syncthreads();

  const int lane = tid & 63;
  const int wid = tid >> 6;
  #pragma unroll
  for (int j = 0; j < 4; ++j) {
    const int fl = wid * 4 + j;
    const int f = f0 + fl;
    const float z = (T[lane][fl] - sfh[fl]) * sfc[fl];
    const float sg = 1.0f / (1.0f + __expf(-z));
    int s0 = (int)(sg * 29.0f);
    s0 = s0 < 0 ? 0 : (s0 > 28 ? 28 : s0);
    const int sp = s0 + 3;
    float Nv[4], lef[4], rig[4];
    Nv[0] = 1.0f;
    #pragma unroll
    for (int r = 1; r <= 3; ++r) {
      lef[r] = sg - knotv(sp + 1 - r);
      rig[r] = knotv(sp + r) - sg;
      float saved = 0.0f;
      #pragma unroll
      for (int jj = 0; jj < r; ++jj) {
        float temp = fdiv_fast(Nv[jj], rig[jj + 1] + lef[r - jj]);
        Nv[jj] = saved + rig[jj + 1] * temp;
        saved = lef[r - jj] * temp;
      }
      Nv[r] = saved;
    }
    const u64 nv =
        (u64)(unsigned short)f2bf(Nv[0])
      | ((u64)(unsigned short)f2bf(Nv[1]) << 16)
      | ((u64)(unsigned short)f2bf(Nv[2]) << 32)
      | ((u64)(unsigned short)f2bf(Nv[3]) << 48);
    nvq[(size_t)f * BATCH + b0 + lane] = nv;
    s0q[(size_t)f * BATCH + b0 + lane] = (unsigned char)s0;
  }
}

// ---------------- A staging ----------------
__device__ __forceinline__ void stage_nv(short* __restrict__ Ab, int cc,
    int stoff, int hi, int bp, int m0,
    unsigned long long nv, int s0, const float* __restrict__ inp)
{
  short* base = Ab + stoff;
  if (cc < 128) {
    const int pp = s0 & 7, ga = s0 >> 3;
    const int s = 16 * pp, shl = s & 63;
    const unsigned long long a = nv << shl;
    const unsigned long long b = (nv >> (63 - shl)) >> 1;
    const bool hs = (s >= 64);
    i64x2 d0, d1, z;
    d0[0] = hs ? 0ll : (long long)a;
    d0[1] = hs ? (long long)a : (long long)b;
    d1[0] = hs ? (long long)b : 0ll;
    d1[1] = 0ll;
    z[0] = 0ll; z[1] = 0ll;
    *(i64x2*)(base + ga * 128) = d0;
    *(i64x2*)(base + ((ga + 1) & 3) * 128) = d1;
    *(i64x2*)(base + ((ga + 2) & 3) * 128) = z;
    *(i64x2*)(base + ((ga + 3) & 3) * 128) = z;
  } else {
    const int sb = (cc - 128) * 64 + hi * 32;
    const float* ip = inp + (size_t)(m0 + bp) * F + sb;
    #pragma unroll
    for (int lq = 0; lq < 4; ++lq) {
      s16x8 h;
      #pragma unroll
      for (int j = 0; j < 8; ++j) h[j] = f2bf(ip[lq * 8 + j]);
      *(s16x8*)(base + lq * 128) = h;
    }
  }
}

// ---------------- main GEMM: v9 core + split-kk intra-wave pipeline ----------------
__global__ __launch_bounds__(256, 2) void kan_gemm_v17(
    const float* __restrict__ inp, const short* __restrict__ Bws,
    const unsigned long long* __restrict__ nvq, const unsigned char* __restrict__ s0q,
    const float* __restrict__ bias, const float* __restrict__ skip_b,
    float* __restrict__ outf, short* __restrict__ Cws)
{
  __shared__ short Abuf[2][8192];

  const int tid = threadIdx.x;
  const int lane = tid & 63;
  const int wid = tid >> 6;
  const int kh = wid >> 1;
  const int nh = wid & 1;

  const int nb = ((blockIdx.x & 7) << 6) | (blockIdx.x >> 3);
  const int mt = nb >> 2, nt = nb & 3;
  const int m0 = mt * 64, n0 = nt * 128;

  const int ci = tid >> 7;
  const int hi = (tid >> 6) & 1;
  const int bp = tid & 63;
  const int mg = bp >> 4, l15b = bp & 15;
  const int stoff = ci * 4096 + ((mg * 2 + hi) * 64 + l15b) * 8;

  f32x4 acc[4][4];
  #pragma unroll
  for (int i = 0; i < 4; ++i)
    #pragma unroll
    for (int j = 0; j < 4; ++j)
      acc[i][j] = (f32x4){0.f, 0.f, 0.f, 0.f};

  const short* bq = Bws + (size_t)(((kh * 4 + nt) * 2 + nh) * 8) * 512 + lane * 8;

#define LOADB(BS) do {                                                          \
    _Pragma("unroll")                                                           \
    for (int nf = 0; nf < 4; ++nf)                                              \
      _Pragma("unroll")                                                         \
      for (int kk = 0; kk < 2; ++kk)                                            \
        BS[nf * 2 + kk] = *(const s16x8*)(bq + (nf * 2 + kk) * 512);            \
    bq += 65536;                                                                \
  } while (0)

#define PREF(NVL, S0L, PTGT) do {                                               \
    const int cc_ = 2 * (PTGT) + ci;                                            \
    if ((PTGT) < NPER && cc_ < 128) {                                           \
      const size_t ix_ = (size_t)(2 * cc_ + hi) * BATCH + m0 + bp;              \
      NVL = nvq[ix_];                                                           \
      S0L = (int)s0q[ix_];                                                      \
    }                                                                           \
  } while (0)

// split-kk pipeline: read kk=0 frags -> MFMA(kk=0) while kk=1 frags load
#define MMAC(AB, BS) do {                                                       \
    s16x8 af0[4], af1[4];                                                       \
    _Pragma("unroll")                                                           \
    for (int mf = 0; mf < 4; ++mf)                                              \
      af0[mf] = *(const s16x8*)&(AB)[kh * 4096 + ((mf * 2 + 0) * 64 + lane) * 8]; \
    __builtin_amdgcn_s_setprio(1);                                              \
    _Pragma("unroll")                                                           \
    for (int mf = 0; mf < 4; ++mf) {                                            \
      if (mf == 0) {                                                            \
        _Pragma("unroll")                                                       \
        for (int m2 = 0; m2 < 4; ++m2)                                          \
          af1[m2] = *(const s16x8*)&(AB)[kh * 4096 + ((m2 * 2 + 1) * 64 + lane) * 8]; \
      }                                                                         \
      _Pragma("unroll")                                                         \
      for (int nf = 0; nf < 4; ++nf)                                            \
        acc[mf][nf] = __builtin_amdgcn_mfma_f32_16x16x32_bf16(                  \
            af0[mf], BS[nf * 2 + 0], acc[mf][nf], 0, 0, 0);                     \
    }                                                                           \
    _Pragma("unroll")                                                           \
    for (int mf = 0; mf < 4; ++mf)                                              \
      _Pragma("unroll")                                                         \
      for (int nf = 0; nf < 4; ++nf)                                            \
        acc[mf][nf] = __builtin_amdgcn_mfma_f32_16x16x32_bf16(                  \
            af1[mf], BS[nf * 2 + 1], acc[mf][nf], 0, 0, 0);                     \
    __builtin_amdgcn_s_setprio(0);                                              \
  } while (0)

#define PERIOD(P_, ACUR, ANXT, BCUR, BNXT, NVU, S0U, NVL, S0L) do {             \
    asm volatile("s_waitcnt lgkmcnt(0)" ::: "memory");                          \
    __builtin_amdgcn_s_barrier();                                               \
    PREF(NVL, S0L, (P_) + 2);                                                   \
    if ((P_) + 1 < NPER) {                                                      \
      LOADB(BNXT);                                                              \
      stage_nv(ANXT, 2 * ((P_) + 1) + ci, stoff, hi, bp, m0, NVU, S0U, inp);    \
    }                                                                           \
    MMAC(ACUR, BCUR);                                                           \
  } while (0)

  s16x8 bA[8], bB[8];
  unsigned long long nvA = 0, nvB = 0;
  int s0A = 0, s0B = 0;

  PREF(nvA, s0A, 0);
  LOADB(bA);
  stage_nv(&Abuf[0][0], 2 * 0 + ci, stoff, hi, bp, m0, nvA, s0A, inp);
  PREF(nvB, s0B, 1);

  for (int p = 0; p < NPER; p += 2) {
    PERIOD(p,     (&Abuf[0][0]), (&Abuf[1][0]), bA, bB, nvB, s0B, nvA, s0A);
    PERIOD(p + 1, (&Abuf[1][0]), (&Abuf[0][0]), bB, bA, nvA, s0A, nvB, s0B);
  }
#undef PERIOD
#undef MMAC
#undef PREF
#undef LOADB

  // ---------- epilogue ----------
  __syncthreads();
  float* red = (float*)&Abuf[0][0];
  const int l15 = lane & 15;
  const int lq = lane >> 4;
  if (kh == 1) {
    #pragma unroll
    for (int mf = 0; mf < 4; ++mf)
      #pragma unroll
      for (int nf = 0; nf < 4; ++nf)
        *(f32x4*)&red[nh * 4096 + (mf * 4 + nf) * 256 + lane * 4] = acc[mf][nf];
  }
  __syncthreads();
  if (kh == 0) {
    #pragma unroll
    for (int nf = 0; nf < 4; ++nf) {
      const int col = n0 + nh * 64 + nf * 16 + l15;
      const float badd = bias[col] + skip_b[col];
      #pragma unroll
      for (int mf = 0; mf < 4; ++mf) {
        f32x4 part = *(const f32x4*)&red[nh * 4096 + (mf * 4 + nf) * 256 + lane * 4];
        const int r0 = m0 + mf * 16 + lq * 4;
        if (Cws) {
          #pragma unroll
          for (int r = 0; r < 4; ++r)
            Cws[(size_t)(r0 + r) * W + col] = f2bf(acc[mf][nf][r] + part[r] + badd);
        } else {
          #pragma unroll
          for (int r = 0; r < 4; ++r)
            outf[(size_t)(r0 + r) * W + col] = acc[mf][nf][r] + part[r] + badd;
        }
      }
    }
  }
}

// ---------------- LN + GeLU from bf16 combined (ws) -> fp32 out ----------------
__global__ __launch_bounds__(256, 1) void ln_gelu_bf(
    const short* __restrict__ Cws, float* __restrict__ out,
    const float* __restrict__ gamma, const float* __restrict__ beta)
{
  const int lane = threadIdx.x & 63;
  const int wid = threadIdx.x >> 6;
  const int row = blockIdx.x * 4 + wid;
  const short* p = Cws + (size_t)row * W + lane * 8;
  s16x8 hv = *(const s16x8*)p;
  float v[8];
  #pragma unroll
  for (int j = 0; j < 8; ++j) v[j] = bf2f((unsigned short)hv[j]);
  float s = 0.f, q = 0.f;
  #pragma unroll
  for (int j = 0; j < 8; ++j) { s += v[j]; q += v[j] * v[j]; }
  #pragma unroll
  for (int m = 1; m < 64; m <<= 1) {
    s += __shfl_xor(s, m);
    q += __shfl_xor(q, m);
  }
  const float mu = s * (1.0f / 512.0f);
  const float var = q * (1.0f / 512.0f) - mu * mu;
  const float inv = rsqrtf(var + 1e-5f);
  const float4 g0 = *(const float4*)(gamma + lane * 8);
  const float4 g1 = *(const float4*)(gamma + lane * 8 + 4);
  const float4 b0 = *(const float4*)(beta + lane * 8);
  const float4 b1 = *(const float4*)(beta + lane * 8 + 4);
  float gm[8] = {g0.x, g0.y, g0.z, g0.w, g1.x, g1.y, g1.z, g1.w};
  float bt[8] = {b0.x, b0.y, b0.z, b0.w, b1.x, b1.y, b1.z, b1.w};
  float o[8];
  #pragma unroll
  for (int j = 0; j < 8; ++j) {
    float x = (v[j] - mu) * inv * gm[j] + bt[j];
    o[j] = 0.5f * x * (1.0f + erff(x * 0.70710678f));
  }
  float* po = out + (size_t)row * W + lane * 8;
  float4 w0 = {o[0], o[1], o[2], o[3]};
  float4 w1 = {o[4], o[5], o[6], o[7]};
  *(float4*)po = w0;
  *(float4*)(po + 4) = w1;
}

// ---------------- LN + GeLU in-place fp32 (mid-tier path) ----------------
__global__ __launch_bounds__(256, 1) void ln_gelu(
    float* __restrict__ out, const float* __restrict__ gamma,
    const float* __restrict__ beta)
{
  const int lane = threadIdx.x & 63;
  const int wid = threadIdx.x >> 6;
  const int row = blockIdx.x * 4 + wid;
  float* p = out + (size_t)row * W + lane * 8;
  float4 a = *(const float4*)p;
  float4 b = *(const float4*)(p + 4);
  float v[8] = {a.x, a.y, a.z, a.w, b.x, b.y, b.z, b.w};
  float s = 0.f, q = 0.f;
  #pragma unroll
  for (int j = 0; j < 8; ++j) { s += v[j]; q += v[j] * v[j]; }
  #pragma unroll
  for (int m = 1; m < 64; m <<= 1) {
    s += __shfl_xor(s, m);
    q += __shfl_xor(q, m);
  }
  const float mu = s * (1.0f / 512.0f);
  const float var = q * (1.0f / 512.0f) - mu * mu;
  const float inv = rsqrtf(var + 1e-5f);
  const float4 g0 = *(const float4*)(gamma + lane * 8);
  const float4 g1 = *(const float4*)(gamma + lane * 8 + 4);
  const float4 b0 = *(const float4*)(beta + lane * 8);
  const float4 b1 = *(const float4*)(beta + lane * 8 + 4);
  float gm[8] = {g0.x, g0.y, g0.z, g0.w, g1.x, g1.y, g1.z, g1.w};
  float bt[8] = {b0.x, b0.y, b0.z, b0.w, b1.x, b1.y, b1.z, b1.w};
  float o[8];
  #pragma unroll
  for (int j = 0; j < 8; ++j) {
    float x = (v[j] - mu) * inv * gm[j] + bt[j];
    o[j] = 0.5f * x * (1.0f + erff(x * 0.70710678f));
  }
  float4 w0 = {o[0], o[1], o[2], o[3]};
  float4 w1 = {o[4], o[5], o[6], o[7]};
  *(float4*)p = w0;
  *(float4*)(p + 4) = w1;
}

// ---------------- fallback GEMM (no ws) — round-2 kernel ----------------
__device__ __forceinline__ void issue_b(int c, int uu, int n0,
                                        const float* __restrict__ coeffs,
                                        const float* __restrict__ skip_w,
                                        float (&r)[4][8]) {
  const float* base = (c < 128) ? (coeffs + (size_t)c * 64 * W)
                                : (skip_w + (size_t)(c - 128) * 64 * W);
  const int kk = (uu >> 6) & 1;
  const int lq = (uu >> 4) & 3;
  const int l15 = uu & 15;
  const int u7 = uu >> 7;
  #pragma unroll
  for (int s = 0; s < 4; ++s) {
    const int w = (2 * s + u7) * 16 + l15;
    const float* p = base + (size_t)(kk * 32 + lq * 8) * W + n0 + w;
    #pragma unroll
    for (int j = 0; j < 8; ++j) r[s][j] = p[(size_t)j * W];
  }
}

__global__ __launch_bounds__(512, 1) void kan_gemm_v2(
    const float* __restrict__ inp, const float* __restrict__ shift,
    const float* __restrict__ lscale, const float* __restrict__ coeffs,
    const float* __restrict__ bias, const float* __restrict__ skip_w,
    const float* __restrict__ skip_b, float* __restrict__ out)
{
  __shared__ short Abuf[2][8192];
  __shared__ short Bbuf[2][8192];
  __shared__ unsigned short sgl[F * 128];

  const int tid = threadIdx.x;
  const int lane = tid & 63;
  const int wid = tid >> 6;
  const int nb = (blockIdx.x & 7) * 32 + (blockIdx.x >> 3);
  const int mt = nb >> 2;
  const int nt = nb & 3;
  const int m0 = mt * 128;
  const int n0 = nt * 128;

  float bpref[4][8];
  if (tid >= 256) issue_b(0, tid - 256, n0, coeffs, skip_w, bpref);

  float* shf = (float*)&Abuf[0][0];
  if (tid < 256) {
    float ls = lscale[tid];
    shf[tid] = fmaxf(ls, 0.0f) + __logf(1.0f + __expf(-fabsf(ls))) + 0.001f;
    shf[256 + tid] = shift[tid];
  }
  __syncthreads();

  {
    const int row = tid & 127;
    const int q = tid >> 7;
    const float* ip = inp + (size_t)(m0 + row) * F + q * 64;
    #pragma unroll
    for (int i = 0; i < 16; ++i) {
      float4 v = *(const float4*)(ip + i * 4);
      float vv[4] = {v.x, v.y, v.z, v.w};
      #pragma unroll
      for (int j = 0; j < 4; ++j) {
        const int f = q * 64 + i * 4 + j;
        const float z = (vv[j] - shf[256 + f]) * shf[f];
        const float sg = 1.0f / (1.0f + __expf(-z));
        sgl[f * 128 + row] = (unsigned short)fminf(sg * 65536.0f, 65535.0f);
      }
    }
  }
  __syncthreads();

  const int wm = wid >> 2;
  const int wn = wid & 3;

  f32x4 acc[4][2];
  #pragma unroll
  for (int i = 0; i < 4; ++i)
    #pragma unroll
    for (int j = 0; j < 2; ++j)
      acc[i][j] = (f32x4){0.f, 0.f, 0.f, 0.f};

  for (int c = 0; c < NCHUNK; ++c) {
    short* Ab = Abuf[c & 1];
    short* Bb = Bbuf[c & 1];

    if (c < 128) {
      s16x8 z = {0, 0, 0, 0, 0, 0, 0, 0};
      ((s16x8*)Ab)[tid * 2] = z;
      ((s16x8*)Ab)[tid * 2 + 1] = z;
    } else if (tid < 256) {
      const int bp = tid & 127, fi = tid >> 7;
      const int sb = (c - 128) * 64 + fi * 32;
      const float* ip = inp + (size_t)(m0 + bp) * F + sb;
      const int rg = bp >> 4, l15b = bp & 15;
      #pragma unroll
      for (int lq2 = 0; lq2 < 4; ++lq2) {
        s16x8 h;
        #pragma unroll
        for (int j = 0; j < 8; ++j) h[j] = f2bf(ip[lq2 * 8 + j]);
        *(s16x8*)&Ab[((rg * 2 + fi) * 64 + lq2 * 16 + l15b) * 8] = h;
      }
    }
    if (tid >= 256) {
      const int uu = tid - 256;
      #pragma unroll
      for (int s = 0; s < 4; ++s) {
        s16x8 h;
        #pragma unroll
        for (int j = 0; j < 8; ++j) h[j] = f2bf(bpref[s][j]);
        *(s16x8*)&Bb[(s * 256 + uu) * 8] = h;
      }
      if (c + 1 < NCHUNK) issue_b(c + 1, uu, n0, coeffs, skip_w, bpref);
    }
    __syncthreads();

    if (c < 128 && tid < 256) {
      const int bp = tid & 127, fi = tid >> 7;
      const int f = 2 * c + fi;
      const float sg = ((float)sgl[f * 128 + bp] + 0.5f) * (1.0f / 65536.0f);
      int s0 = (int)floorf(sg * 29.0f);
      s0 = s0 < 0 ? 0 : (s0 > 28 ? 28 : s0);
      const int sp = s0 + 3;
      float Nv[4], lef[4], rig[4];
      Nv[0] = 1.0f;
      #pragma unroll
      for (int r = 1; r <= 3; ++r) {
        lef[r] = sg - knotv(sp + 1 - r);
        rig[r] = knotv(sp + r) - sg;
        float saved = 0.0f;
        #pragma unroll
        for (int j = 0; j < r; ++j) {
          float temp = fdiv_fast(Nv[j], rig[j + 1] + lef[r - j]);
          Nv[j] = saved + rig[j + 1] * temp;
          saved = lef[r - j] * temp;
        }
        Nv[r] = saved;
      }
      const int rg = bp >> 4, l15b = bp & 15;
      #pragma unroll
      for (int t = 0; t < 4; ++t) {
        const int g = s0 + t;
        Ab[((rg * 2 + fi) * 64 + (g >> 3) * 16 + l15b) * 8 + (g & 7)] = f2bf(Nv[t]);
      }
    }
    s16x8 bfv[2][2];
    #pragma unroll
    for (int nf = 0; nf < 2; ++nf)
      #pragma unroll
      for (int kk = 0; kk < 2; ++kk)
        bfv[nf][kk] = *(const s16x8*)&Bb[(((wn * 2 + nf) * 2 + kk) * 64 + lane) * 8];
    __syncthreads();

    #pragma unroll
    for (int kk = 0; kk < 2; ++kk) {
      #pragma unroll
      for (int mf = 0; mf < 4; ++mf) {
        s16x8 af = *(const s16x8*)&Ab[(((wm * 4 + mf) * 2 + kk) * 64 + lane) * 8];
        #pragma unroll
        for (int nf = 0; nf < 2; ++nf)
          acc[mf][nf] = __builtin_amdgcn_mfma_f32_16x16x32_bf16(af, bfv[nf][kk], acc[mf][nf], 0, 0, 0);
      }
    }
  }

  const int l15 = lane & 15;
  const int lq = lane >> 4;
  #pragma unroll
  for (int nf = 0; nf < 2; ++nf) {
    const int col = n0 + wn * 32 + nf * 16 + l15;
    const float badd = bias[col] + skip_b[col];
    #pragma unroll
    for (int mf = 0; mf < 4; ++mf) {
      const int r0 = m0 + wm * 64 + mf * 16 + lq * 4;
      #pragma unroll
      for (int r = 0; r < 4; ++r)
        out[(size_t)(r0 + r) * W + col] = acc[mf][nf][r] + badd;
    }
  }
}

extern "C" void kernel_launch(void* const* d_in, const int* in_sizes, int n_in,
                              void* d_out, int out_size, void* d_ws, size_t ws_size,
                              hipStream_t stream) {
  (void)in_sizes; (void)n_in; (void)out_size;
  const float* inp    = (const float*)d_in[0];
  const float* shift  = (const float*)d_in[1];
  const float* lscale = (const float*)d_in[2];
  const float* coeffs = (const float*)d_in[3];
  const float* bias   = (const float*)d_in[4];
  const float* skip_w = (const float*)d_in[5];
  const float* skip_b = (const float*)d_in[6];
  const float* gamma  = (const float*)d_in[7];
  const float* beta   = (const float*)d_in[8];
  float* out = (float*)d_out;

  const size_t needB  = (size_t)NCHUNK * 4 * 16384;
  const size_t needNV = (size_t)F * BATCH * 8;
  const size_t needS0 = (size_t)F * BATCH;
  const size_t needC  = (size_t)BATCH * W * 2;

  if (ws_size >= needB + needNV + needS0 + needC) {
    short* Bws = (short*)d_ws;
    unsigned long long* nvq = (unsigned long long*)((char*)d_ws + needB);
    unsigned char* s0q = (unsigned char*)((char*)d_ws + needB + needNV);
    short* Cws = (short*)((char*)d_ws + needB + needNV + needS0);
    pre_build<<<dim3(4160), dim3(256), 0, stream>>>(
        coeffs, skip_w, inp, shift, lscale, Bws, nvq, s0q);
    kan_gemm_v17<<<dim3(512), dim3(256), 0, stream>>>(
        inp, Bws, nvq, s0q, bias, skip_b, nullptr, Cws);
    ln_gelu_bf<<<dim3(BATCH / 4), dim3(256), 0, stream>>>(Cws, out, gamma, beta);
  } else if (ws_size >= needB + needNV + needS0) {
    short* Bws = (short*)d_ws;
    unsigned long long* nvq = (unsigned long long*)((char*)d_ws + needB);
    unsigned char* s0q = (unsigned char*)((char*)d_ws + needB + needNV);
    pre_build<<<dim3(4160), dim3(256), 0, stream>>>(
        coeffs, skip_w, inp, shift, lscale, Bws, nvq, s0q);
    kan_gemm_v17<<<dim3(512), dim3(256), 0, stream>>>(
        inp, Bws, nvq, s0q, bias, skip_b, out, nullptr);
    ln_gelu<<<dim3(BATCH / 4), dim3(256), 0, stream>>>(out, gamma, beta);
  } else {
    kan_gemm_v2<<<dim3(256), dim3(512), 0, stream>>>(
        inp, shift, lscale, coeffs, bias, skip_w, skip_b, out);
    ln_gelu<<<dim3(BATCH / 4), dim3(256), 0, stream>>>(out, gamma, beta);
  }
}

// Round 21
// 87.042 us; speedup vs baseline: 1.0872x; 1.0021x over previous
//
#include <hip/hip_runtime.h>
#include <hip/hip_bf16.h>
#include <math.h>

#define BATCH 8192
#define F 256
#define G 32
#define W 512
#define NCHUNK 132
#define NPER 66

typedef float f32x4 __attribute__((ext_vector_type(4)));
typedef short s16x8 __attribute__((ext_vector_type(8)));
typedef long long i64x2 __attribute__((ext_vector_type(2)));
typedef unsigned long long u64;

__device__ __forceinline__ short f2bf(float f) {
  unsigned int u = __builtin_bit_cast(unsigned int, f);
  u += 0x7fffu + ((u >> 16) & 1u);
  return (short)(u >> 16);
}

__device__ __forceinline__ float bf2f(unsigned short h) {
  unsigned int u = ((unsigned int)h) << 16;
  return __builtin_bit_cast(float, u);
}

__device__ __forceinline__ float knotv(int i) {
  int j = i - 3;
  j = j < 0 ? 0 : (j > 29 ? 29 : j);
  return (float)j * (1.0f / 29.0f);
}

__device__ __forceinline__ float fdiv_fast(float a, float b) {
  return a * __builtin_amdgcn_rcpf(b);
}

// ---------------- merged pre-pass ----------------
__global__ __launch_bounds__(256) void pre_build(
    const float* __restrict__ coeffs, const float* __restrict__ skip_w,
    const float* __restrict__ inp, const float* __restrict__ shift,
    const float* __restrict__ lscale,
    short* __restrict__ Bws, unsigned long long* __restrict__ nvq,
    unsigned char* __restrict__ s0q)
{
  __shared__ float T[64][17];
  __shared__ float sfc[16], sfh[16];
  const int tid = threadIdx.x;

  if (blockIdx.x < 2112) {
    const int gid = blockIdx.x * 256 + tid;
    const int lane = gid & 63;
    const int kk = (gid >> 6) & 1;
    const int nf = (gid >> 7) & 3;
    const int wn = (gid >> 9) & 1;
    const int nt = (gid >> 10) & 3;
    const int c  = gid >> 12;
    const int w  = nt * 128 + wn * 64 + nf * 16 + (lane & 15);
    const int kl = kk * 32 + (lane >> 4) * 8;
    const float* src = (c < 128) ? (coeffs + (size_t)(c * 64 + kl) * W + w)
                                 : (skip_w + (size_t)((c - 128) * 64 + kl) * W + w);
    s16x8 h;
    #pragma unroll
    for (int j = 0; j < 8; ++j) h[j] = f2bf(src[(size_t)j * W]);
    ((s16x8*)Bws)[gid] = h;
    return;
  }

  const int bb = blockIdx.x - 2112;
  const int b0 = (bb & 127) * 64;
  const int f0 = (bb >> 7) * 16;

  {
    const int r = tid >> 2, q = tid & 3;
    float4 v = *(const float4*)(inp + (size_t)(b0 + r) * F + f0 + q * 4);
    T[r][q * 4 + 0] = v.x;
    T[r][q * 4 + 1] = v.y;
    T[r][q * 4 + 2] = v.z;
    T[r][q * 4 + 3] = v.w;
  }
  if (tid < 16) {
    float ls = lscale[f0 + tid];
    sfc[tid] = fmaxf(ls, 0.0f) + __logf(1.0f + __expf(-fabsf(ls))) + 0.001f;
    sfh[tid] = shift[f0 + tid];
  }
  __syncthreads();

  const int lane = tid & 63;
  const int wid = tid >> 6;
  #pragma unroll
  for (int j = 0; j < 4; ++j) {
    const int fl = wid * 4 + j;
    const int f = f0 + fl;
    const float z = (T[lane][fl] - sfh[fl]) * sfc[fl];
    const float sg = 1.0f / (1.0f + __expf(-z));
    int s0 = (int)(sg * 29.0f);
    s0 = s0 < 0 ? 0 : (s0 > 28 ? 28 : s0);
    const int sp = s0 + 3;
    float Nv[4], lef[4], rig[4];
    Nv[0] = 1.0f;
    #pragma unroll
    for (int r = 1; r <= 3; ++r) {
      lef[r] = sg - knotv(sp + 1 - r);
      rig[r] = knotv(sp + r) - sg;
      float saved = 0.0f;
      #pragma unroll
      for (int jj = 0; jj < r; ++jj) {
        float temp = fdiv_fast(Nv[jj], rig[jj + 1] + lef[r - jj]);
        Nv[jj] = saved + rig[jj + 1] * temp;
        saved = lef[r - jj] * temp;
      }
      Nv[r] = saved;
    }
    const u64 nv =
        (u64)(unsigned short)f2bf(Nv[0])
      | ((u64)(unsigned short)f2bf(Nv[1]) << 16)
      | ((u64)(unsigned short)f2bf(Nv[2]) << 32)
      | ((u64)(unsigned short)f2bf(Nv[3]) << 48);
    nvq[(size_t)f * BATCH + b0 + lane] = nv;
    s0q[(size_t)f * BATCH + b0 + lane] = (unsigned char)s0;
  }
}

// ---------------- A staging ----------------
__device__ __forceinline__ void stage_nv(short* __restrict__ Ab, int cc,
    int stoff, int hi, int bp, int m0,
    unsigned long long nv, int s0, const float* __restrict__ inp)
{
  short* base = Ab + stoff;
  if (cc < 128) {
    const int pp = s0 & 7, ga = s0 >> 3;
    const int s = 16 * pp, shl = s & 63;
    const unsigned long long a = nv << shl;
    const unsigned long long b = (nv >> (63 - shl)) >> 1;
    const bool hs = (s >= 64);
    i64x2 d0, d1, z;
    d0[0] = hs ? 0ll : (long long)a;
    d0[1] = hs ? (long long)a : (long long)b;
    d1[0] = hs ? (long long)b : 0ll;
    d1[1] = 0ll;
    z[0] = 0ll; z[1] = 0ll;
    *(i64x2*)(base + ga * 128) = d0;
    *(i64x2*)(base + ((ga + 1) & 3) * 128) = d1;
    *(i64x2*)(base + ((ga + 2) & 3) * 128) = z;
    *(i64x2*)(base + ((ga + 3) & 3) * 128) = z;
  } else {
    const int sb = (cc - 128) * 64 + hi * 32;
    const float* ip = inp + (size_t)(m0 + bp) * F + sb;
    #pragma unroll
    for (int lq = 0; lq < 4; ++lq) {
      s16x8 h;
      #pragma unroll
      for (int j = 0; j < 8; ++j) h[j] = f2bf(ip[lq * 8 + j]);
      *(s16x8*)(base + lq * 128) = h;
    }
  }
}

// ---------------- main GEMM: v9 core + split-kk intra-wave pipeline ----------------
__global__ __launch_bounds__(256, 2) void kan_gemm_v17(
    const float* __restrict__ inp, const short* __restrict__ Bws,
    const unsigned long long* __restrict__ nvq, const unsigned char* __restrict__ s0q,
    const float* __restrict__ bias, const float* __restrict__ skip_b,
    float* __restrict__ outf, short* __restrict__ Cws)
{
  __shared__ short Abuf[2][8192];

  const int tid = threadIdx.x;
  const int lane = tid & 63;
  const int wid = tid >> 6;
  const int kh = wid >> 1;
  const int nh = wid & 1;

  const int nb = ((blockIdx.x & 7) << 6) | (blockIdx.x >> 3);
  const int mt = nb >> 2, nt = nb & 3;
  const int m0 = mt * 64, n0 = nt * 128;

  const int ci = tid >> 7;
  const int hi = (tid >> 6) & 1;
  const int bp = tid & 63;
  const int mg = bp >> 4, l15b = bp & 15;
  const int stoff = ci * 4096 + ((mg * 2 + hi) * 64 + l15b) * 8;

  f32x4 acc[4][4];
  #pragma unroll
  for (int i = 0; i < 4; ++i)
    #pragma unroll
    for (int j = 0; j < 4; ++j)
      acc[i][j] = (f32x4){0.f, 0.f, 0.f, 0.f};

  const short* bq = Bws + (size_t)(((kh * 4 + nt) * 2 + nh) * 8) * 512 + lane * 8;

#define LOADB(BS) do {                                                          \
    _Pragma("unroll")                                                           \
    for (int nf = 0; nf < 4; ++nf)                                              \
      _Pragma("unroll")                                                         \
      for (int kk = 0; kk < 2; ++kk)                                            \
        BS[nf * 2 + kk] = *(const s16x8*)(bq + (nf * 2 + kk) * 512);            \
    bq += 65536;                                                                \
  } while (0)

#define PREF(NVL, S0L, PTGT) do {                                               \
    const int cc_ = 2 * (PTGT) + ci;                                            \
    if ((PTGT) < NPER && cc_ < 128) {                                           \
      const size_t ix_ = (size_t)(2 * cc_ + hi) * BATCH + m0 + bp;              \
      NVL = nvq[ix_];                                                           \
      S0L = (int)s0q[ix_];                                                      \
    }                                                                           \
  } while (0)

// split-kk pipeline: read kk=0 frags -> MFMA(kk=0) while kk=1 frags load
#define MMAC(AB, BS) do {                                                       \
    s16x8 af0[4], af1[4];                                                       \
    _Pragma("unroll")                                                           \
    for (int mf = 0; mf < 4; ++mf)                                              \
      af0[mf] = *(const s16x8*)&(AB)[kh * 4096 + ((mf * 2 + 0) * 64 + lane) * 8]; \
    __builtin_amdgcn_s_setprio(1);                                              \
    _Pragma("unroll")                                                           \
    for (int mf = 0; mf < 4; ++mf) {                                            \
      if (mf == 0) {                                                            \
        _Pragma("unroll")                                                       \
        for (int m2 = 0; m2 < 4; ++m2)                                          \
          af1[m2] = *(const s16x8*)&(AB)[kh * 4096 + ((m2 * 2 + 1) * 64 + lane) * 8]; \
      }                                                                         \
      _Pragma("unroll")                                                         \
      for (int nf = 0; nf < 4; ++nf)                                            \
        acc[mf][nf] = __builtin_amdgcn_mfma_f32_16x16x32_bf16(                  \
            af0[mf], BS[nf * 2 + 0], acc[mf][nf], 0, 0, 0);                     \
    }                                                                           \
    _Pragma("unroll")                                                           \
    for (int mf = 0; mf < 4; ++mf)                                              \
      _Pragma("unroll")                                                         \
      for (int nf = 0; nf < 4; ++nf)                                            \
        acc[mf][nf] = __builtin_amdgcn_mfma_f32_16x16x32_bf16(                  \
            af1[mf], BS[nf * 2 + 1], acc[mf][nf], 0, 0, 0);                     \
    __builtin_amdgcn_s_setprio(0);                                              \
  } while (0)

#define PERIOD(P_, ACUR, ANXT, BCUR, BNXT, NVU, S0U, NVL, S0L) do {             \
    asm volatile("s_waitcnt lgkmcnt(0)" ::: "memory");                          \
    __builtin_amdgcn_s_barrier();                                               \
    PREF(NVL, S0L, (P_) + 2);                                                   \
    if ((P_) + 1 < NPER) {                                                      \
      LOADB(BNXT);                                                              \
      stage_nv(ANXT, 2 * ((P_) + 1) + ci, stoff, hi, bp, m0, NVU, S0U, inp);    \
    }                                                                           \
    MMAC(ACUR, BCUR);                                                           \
  } while (0)

  s16x8 bA[8], bB[8];
  unsigned long long nvA = 0, nvB = 0;
  int s0A = 0, s0B = 0;

  PREF(nvA, s0A, 0);
  LOADB(bA);
  stage_nv(&Abuf[0][0], 2 * 0 + ci, stoff, hi, bp, m0, nvA, s0A, inp);
  PREF(nvB, s0B, 1);

  for (int p = 0; p < NPER; p += 2) {
    PERIOD(p,     (&Abuf[0][0]), (&Abuf[1][0]), bA, bB, nvB, s0B, nvA, s0A);
    PERIOD(p + 1, (&Abuf[1][0]), (&Abuf[0][0]), bB, bA, nvA, s0A, nvB, s0B);
  }
#undef PERIOD
#undef MMAC
#undef PREF
#undef LOADB

  // ---------- epilogue ----------
  __syncthreads();
  float* red = (float*)&Abuf[0][0];
  const int l15 = lane & 15;
  const int lq = lane >> 4;
  if (kh == 1) {
    #pragma unroll
    for (int mf = 0; mf < 4; ++mf)
      #pragma unroll
      for (int nf = 0; nf < 4; ++nf)
        *(f32x4*)&red[nh * 4096 + (mf * 4 + nf) * 256 + lane * 4] = acc[mf][nf];
  }
  __syncthreads();
  if (kh == 0) {
    #pragma unroll
    for (int nf = 0; nf < 4; ++nf) {
      const int col = n0 + nh * 64 + nf * 16 + l15;
      const float badd = bias[col] + skip_b[col];
      #pragma unroll
      for (int mf = 0; mf < 4; ++mf) {
        f32x4 part = *(const f32x4*)&red[nh * 4096 + (mf * 4 + nf) * 256 + lane * 4];
        const int r0 = m0 + mf * 16 + lq * 4;
        if (Cws) {
          #pragma unroll
          for (int r = 0; r < 4; ++r)
            Cws[(size_t)(r0 + r) * W + col] = f2bf(acc[mf][nf][r] + part[r] + badd);
        } else {
          #pragma unroll
          for (int r = 0; r < 4; ++r)
            outf[(size_t)(r0 + r) * W + col] = acc[mf][nf][r] + part[r] + badd;
        }
      }
    }
  }
}

// ---------------- LN + GeLU from bf16 combined (ws) -> fp32 out ----------------
__global__ __launch_bounds__(256, 1) void ln_gelu_bf(
    const short* __restrict__ Cws, float* __restrict__ out,
    const float* __restrict__ gamma, const float* __restrict__ beta)
{
  const int lane = threadIdx.x & 63;
  const int wid = threadIdx.x >> 6;
  const int row = blockIdx.x * 4 + wid;
  const short* p = Cws + (size_t)row * W + lane * 8;
  s16x8 hv = *(const s16x8*)p;
  float v[8];
  #pragma unroll
  for (int j = 0; j < 8; ++j) v[j] = bf2f((unsigned short)hv[j]);
  float s = 0.f, q = 0.f;
  #pragma unroll
  for (int j = 0; j < 8; ++j) { s += v[j]; q += v[j] * v[j]; }
  #pragma unroll
  for (int m = 1; m < 64; m <<= 1) {
    s += __shfl_xor(s, m);
    q += __shfl_xor(q, m);
  }
  const float mu = s * (1.0f / 512.0f);
  const float var = q * (1.0f / 512.0f) - mu * mu;
  const float inv = rsqrtf(var + 1e-5f);
  const float4 g0 = *(const float4*)(gamma + lane * 8);
  const float4 g1 = *(const float4*)(gamma + lane * 8 + 4);
  const float4 b0 = *(const float4*)(beta + lane * 8);
  const float4 b1 = *(const float4*)(beta + lane * 8 + 4);
  float gm[8] = {g0.x, g0.y, g0.z, g0.w, g1.x, g1.y, g1.z, g1.w};
  float bt[8] = {b0.x, b0.y, b0.z, b0.w, b1.x, b1.y, b1.z, b1.w};
  float o[8];
  #pragma unroll
  for (int j = 0; j < 8; ++j) {
    float x = (v[j] - mu) * inv * gm[j] + bt[j];
    o[j] = 0.5f * x * (1.0f + erff(x * 0.70710678f));
  }
  float* po = out + (size_t)row * W + lane * 8;
  float4 w0 = {o[0], o[1], o[2], o[3]};
  float4 w1 = {o[4], o[5], o[6], o[7]};
  *(float4*)po = w0;
  *(float4*)(po + 4) = w1;
}

// ---------------- LN + GeLU in-place fp32 (mid-tier path) ----------------
__global__ __launch_bounds__(256, 1) void ln_gelu(
    float* __restrict__ out, const float* __restrict__ gamma,
    const float* __restrict__ beta)
{
  const int lane = threadIdx.x & 63;
  const int wid = threadIdx.x >> 6;
  const int row = blockIdx.x * 4 + wid;
  float* p = out + (size_t)row * W + lane * 8;
  float4 a = *(const float4*)p;
  float4 b = *(const float4*)(p + 4);
  float v[8] = {a.x, a.y, a.z, a.w, b.x, b.y, b.z, b.w};
  float s = 0.f, q = 0.f;
  #pragma unroll
  for (int j = 0; j < 8; ++j) { s += v[j]; q += v[j] * v[j]; }
  #pragma unroll
  for (int m = 1; m < 64; m <<= 1) {
    s += __shfl_xor(s, m);
    q += __shfl_xor(q, m);
  }
  const float mu = s * (1.0f / 512.0f);
  const float var = q * (1.0f / 512.0f) - mu * mu;
  const float inv = rsqrtf(var + 1e-5f);
  const float4 g0 = *(const float4*)(gamma + lane * 8);
  const float4 g1 = *(const float4*)(gamma + lane * 8 + 4);
  const float4 b0 = *(const float4*)(beta + lane * 8);
  const float4 b1 = *(const float4*)(beta + lane * 8 + 4);
  float gm[8] = {g0.x, g0.y, g0.z, g0.w, g1.x, g1.y, g1.z, g1.w};
  float bt[8] = {b0.x, b0.y, b0.z, b0.w, b1.x, b1.y, b1.z, b1.w};
  float o[8];
  #pragma unroll
  for (int j = 0; j < 8; ++j) {
    float x = (v[j] - mu) * inv * gm[j] + bt[j];
    o[j] = 0.5f * x * (1.0f + erff(x * 0.70710678f));
  }
  float4 w0 = {o[0], o[1], o[2], o[3]};
  float4 w1 = {o[4], o[5], o[6], o[7]};
  *(float4*)p = w0;
  *(float4*)(p + 4) = w1;
}

// ---------------- fallback GEMM (no ws) — round-2 kernel ----------------
__device__ __forceinline__ void issue_b(int c, int uu, int n0,
                                        const float* __restrict__ coeffs,
                                        const float* __restrict__ skip_w,
                                        float (&r)[4][8]) {
  const float* base = (c < 128) ? (coeffs + (size_t)c * 64 * W)
                                : (skip_w + (size_t)(c - 128) * 64 * W);
  const int kk = (uu >> 6) & 1;
  const int lq = (uu >> 4) & 3;
  const int l15 = uu & 15;
  const int u7 = uu >> 7;
  #pragma unroll
  for (int s = 0; s < 4; ++s) {
    const int w = (2 * s + u7) * 16 + l15;
    const float* p = base + (size_t)(kk * 32 + lq * 8) * W + n0 + w;
    #pragma unroll
    for (int j = 0; j < 8; ++j) r[s][j] = p[(size_t)j * W];
  }
}

__global__ __launch_bounds__(512, 1) void kan_gemm_v2(
    const float* __restrict__ inp, const float* __restrict__ shift,
    const float* __restrict__ lscale, const float* __restrict__ coeffs,
    const float* __restrict__ bias, const float* __restrict__ skip_w,
    const float* __restrict__ skip_b, float* __restrict__ out)
{
  __shared__ short Abuf[2][8192];
  __shared__ short Bbuf[2][8192];
  __shared__ unsigned short sgl[F * 128];

  const int tid = threadIdx.x;
  const int lane = tid & 63;
  const int wid = tid >> 6;
  const int nb = (blockIdx.x & 7) * 32 + (blockIdx.x >> 3);
  const int mt = nb >> 2;
  const int nt = nb & 3;
  const int m0 = mt * 128;
  const int n0 = nt * 128;

  float bpref[4][8];
  if (tid >= 256) issue_b(0, tid - 256, n0, coeffs, skip_w, bpref);

  float* shf = (float*)&Abuf[0][0];
  if (tid < 256) {
    float ls = lscale[tid];
    shf[tid] = fmaxf(ls, 0.0f) + __logf(1.0f + __expf(-fabsf(ls))) + 0.001f;
    shf[256 + tid] = shift[tid];
  }
  __syncthreads();

  {
    const int row = tid & 127;
    const int q = tid >> 7;
    const float* ip = inp + (size_t)(m0 + row) * F + q * 64;
    #pragma unroll
    for (int i = 0; i < 16; ++i) {
      float4 v = *(const float4*)(ip + i * 4);
      float vv[4] = {v.x, v.y, v.z, v.w};
      #pragma unroll
      for (int j = 0; j < 4; ++j) {
        const int f = q * 64 + i * 4 + j;
        const float z = (vv[j] - shf[256 + f]) * shf[f];
        const float sg = 1.0f / (1.0f + __expf(-z));
        sgl[f * 128 + row] = (unsigned short)fminf(sg * 65536.0f, 65535.0f);
      }
    }
  }
  __syncthreads();

  const int wm = wid >> 2;
  const int wn = wid & 3;

  f32x4 acc[4][2];
  #pragma unroll
  for (int i = 0; i < 4; ++i)
    #pragma unroll
    for (int j = 0; j < 2; ++j)
      acc[i][j] = (f32x4){0.f, 0.f, 0.f, 0.f};

  for (int c = 0; c < NCHUNK; ++c) {
    short* Ab = Abuf[c & 1];
    short* Bb = Bbuf[c & 1];

    if (c < 128) {
      s16x8 z = {0, 0, 0, 0, 0, 0, 0, 0};
      ((s16x8*)Ab)[tid * 2] = z;
      ((s16x8*)Ab)[tid * 2 + 1] = z;
    } else if (tid < 256) {
      const int bp = tid & 127, fi = tid >> 7;
      const int sb = (c - 128) * 64 + fi * 32;
      const float* ip = inp + (size_t)(m0 + bp) * F + sb;
      const int rg = bp >> 4, l15b = bp & 15;
      #pragma unroll
      for (int lq2 = 0; lq2 < 4; ++lq2) {
        s16x8 h;
        #pragma unroll
        for (int j = 0; j < 8; ++j) h[j] = f2bf(ip[lq2 * 8 + j]);
        *(s16x8*)&Ab[((rg * 2 + fi) * 64 + lq2 * 16 + l15b) * 8] = h;
      }
    }
    if (tid >= 256) {
      const int uu = tid - 256;
      #pragma unroll
      for (int s = 0; s < 4; ++s) {
        s16x8 h;
        #pragma unroll
        for (int j = 0; j < 8; ++j) h[j] = f2bf(bpref[s][j]);
        *(s16x8*)&Bb[(s * 256 + uu) * 8] = h;
      }
      if (c + 1 < NCHUNK) issue_b(c + 1, uu, n0, coeffs, skip_w, bpref);
    }
    __syncthreads();

    if (c < 128 && tid < 256) {
      const int bp = tid & 127, fi = tid >> 7;
      const int f = 2 * c + fi;
      const float sg = ((float)sgl[f * 128 + bp] + 0.5f) * (1.0f / 65536.0f);
      int s0 = (int)floorf(sg * 29.0f);
      s0 = s0 < 0 ? 0 : (s0 > 28 ? 28 : s0);
      const int sp = s0 + 3;
      float Nv[4], lef[4], rig[4];
      Nv[0] = 1.0f;
      #pragma unroll
      for (int r = 1; r <= 3; ++r) {
        lef[r] = sg - knotv(sp + 1 - r);
        rig[r] = knotv(sp + r) - sg;
        float saved = 0.0f;
        #pragma unroll
        for (int j = 0; j < r; ++j) {
          float temp = fdiv_fast(Nv[j], rig[j + 1] + lef[r - j]);
          Nv[j] = saved + rig[j + 1] * temp;
          saved = lef[r - j] * temp;
        }
        Nv[r] = saved;
      }
      const int rg = bp >> 4, l15b = bp & 15;
      #pragma unroll
      for (int t = 0; t < 4; ++t) {
        const int g = s0 + t;
        Ab[((rg * 2 + fi) * 64 + (g >> 3) * 16 + l15b) * 8 + (g & 7)] = f2bf(Nv[t]);
      }
    }
    s16x8 bfv[2][2];
    #pragma unroll
    for (int nf = 0; nf < 2; ++nf)
      #pragma unroll
      for (int kk = 0; kk < 2; ++kk)
        bfv[nf][kk] = *(const s16x8*)&Bb[(((wn * 2 + nf) * 2 + kk) * 64 + lane) * 8];
    __syncthreads();

    #pragma unroll
    for (int kk = 0; kk < 2; ++kk) {
      #pragma unroll
      for (int mf = 0; mf < 4; ++mf) {
        s16x8 af = *(const s16x8*)&Ab[(((wm * 4 + mf) * 2 + kk) * 64 + lane) * 8];
        #pragma unroll
        for (int nf = 0; nf < 2; ++nf)
          acc[mf][nf] = __builtin_amdgcn_mfma_f32_16x16x32_bf16(af, bfv[nf][kk], acc[mf][nf], 0, 0, 0);
      }
    }
  }

  const int l15 = lane & 15;
  const int lq = lane >> 4;
  #pragma unroll
  for (int nf = 0; nf < 2; ++nf) {
    const int col = n0 + wn * 32 + nf * 16 + l15;
    const float badd = bias[col] + skip_b[col];
    #pragma unroll
    for (int mf = 0; mf < 4; ++mf) {
      const int r0 = m0 + wm * 64 + mf * 16 + lq * 4;
      #pragma unroll
      for (int r = 0; r < 4; ++r)
        out[(size_t)(r0 + r) * W + col] = acc[mf][nf][r] + badd;
    }
  }
}

extern "C" void kernel_launch(void* const* d_in, const int* in_sizes, int n_in,
                              void* d_out, int out_size, void* d_ws, size_t ws_size,
                              hipStream_t stream) {
  (void)in_sizes; (void)n_in; (void)out_size;
  const float* inp    = (const float*)d_in[0];
  const float* shift  = (const float*)d_in[1];
  const float* lscale = (const float*)d_in[2];
  const float* coeffs = (const float*)d_in[3];
  const float* bias   = (const float*)d_in[4];
  const float* skip_w = (const float*)d_in[5];
  const float* skip_b = (const float*)d_in[6];
  const float* gamma  = (const float*)d_in[7];
  const float* beta   = (const float*)d_in[8];
  float* out = (float*)d_out;

  const size_t needB  = (size_t)NCHUNK * 4 * 16384;
  const size_t needNV = (size_t)F * BATCH * 8;
  const size_t needS0 = (size_t)F * BATCH;
  const size_t needC  = (size_t)BATCH * W * 2;

  if (ws_size >= needB + needNV + needS0 + needC) {
    short* Bws = (short*)d_ws;
    unsigned long long* nvq = (unsigned long long*)((char*)d_ws + needB);
    unsigned char* s0q = (unsigned char*)((char*)d_ws + needB + needNV);
    short* Cws = (short*)((char*)d_ws + needB + needNV + needS0);
    pre_build<<<dim3(4160), dim3(256), 0, stream>>>(
        coeffs, skip_w, inp, shift, lscale, Bws, nvq, s0q);
    kan_gemm_v17<<<dim3(512), dim3(256), 0, stream>>>(
        inp, Bws, nvq, s0q, bias, skip_b, nullptr, Cws);
    ln_gelu_bf<<<dim3(BATCH / 4), dim3(256), 0, stream>>>(Cws, out, gamma, beta);
  } else if (ws_size >= needB + needNV + needS0) {
    short* Bws = (short*)d_ws;
    unsigned long long* nvq = (unsigned long long*)((char*)d_ws + needB);
    unsigned char* s0q = (unsigned char*)((char*)d_ws + needB + needNV);
    pre_build<<<dim3(4160), dim3(256), 0, stream>>>(
        coeffs, skip_w, inp, shift, lscale, Bws, nvq, s0q);
    kan_gemm_v17<<<dim3(512), dim3(256), 0, stream>>>(
        inp, Bws, nvq, s0q, bias, skip_b, out, nullptr);
    ln_gelu<<<dim3(BATCH / 4), dim3(256), 0, stream>>>(out, gamma, beta);
  } else {
    kan_gemm_v2<<<dim3(256), dim3(512), 0, stream>>>(
        inp, shift, lscale, coeffs, bias, skip_w, skip_b, out);
    ln_gelu<<<dim3(BATCH / 4), dim3(256), 0, stream>>>(out, gamma, beta);
  }
}